// Round 4
// baseline (366.173 us; speedup 1.0000x reference)
//
#include <hip/hip_runtime.h>
#include <math.h>

#define B_SZ 32
#define L_SZ 32768
#define T_SZ 1024
#define PS_SZ 32
#define D_SZ 256

typedef float f32x4 __attribute__((ext_vector_type(4)));
typedef short s16x8 __attribute__((ext_vector_type(8)));
typedef unsigned short u16x8 __attribute__((ext_vector_type(8)));
typedef unsigned short u16x4 __attribute__((ext_vector_type(4)));

__device__ __forceinline__ unsigned short f2bf(float f) {
  union { float f; unsigned int u; } v; v.f = f;
  unsigned int r = v.u + 0x7FFFu + ((v.u >> 16) & 1u);
  return (unsigned short)(r >> 16);
}

// ---------------- InstanceNorm pass 1: partial sums (8 blocks per row) ----------------
__global__ __launch_bounds__(256) void norm_stats(const float* __restrict__ x,
                                                  float* __restrict__ sget) {
  const int b = blockIdx.x >> 3;
  const float* p = x + (size_t)b * L_SZ + (size_t)(blockIdx.x & 7) * 4096;
  float s = 0.f, ss = 0.f;
#pragma unroll
  for (int i = 0; i < 4; ++i) {
    float4 f = ((const float4*)p)[threadIdx.x + i * 256];
    s += f.x + f.y + f.z + f.w;
    ss += f.x * f.x + f.y * f.y + f.z * f.z + f.w * f.w;
  }
#pragma unroll
  for (int off = 32; off >= 1; off >>= 1) {
    s += __shfl_down(s, off);
    ss += __shfl_down(ss, off);
  }
  __shared__ float rs[4], rss[4];
  const int wid = threadIdx.x >> 6, lane = threadIdx.x & 63;
  if (lane == 0) { rs[wid] = s; rss[wid] = ss; }
  __syncthreads();
  if (threadIdx.x == 0) {
    atomicAdd(&sget[b * 2],     rs[0] + rs[1] + rs[2] + rs[3]);
    atomicAdd(&sget[b * 2 + 1], rss[0] + rss[1] + rss[2] + rss[3]);
  }
}

// ---------------- InstanceNorm pass 2: normalize -> xn fp32 + xbf bf16 ----------------
__global__ __launch_bounds__(256) void norm_apply(const float* __restrict__ x,
                                                  const float* __restrict__ sget,
                                                  float* __restrict__ xn,
                                                  unsigned short* __restrict__ xbf) {
  const int gid = blockIdx.x * 256 + threadIdx.x;
  const size_t base = (size_t)gid * 4;
  const int b = (int)(base >> 15);
  const float S = sget[b * 2], SS = sget[b * 2 + 1];
  const float mean = S * (1.f / (float)L_SZ);
  const float var = (SS - S * mean) * (1.f / (float)(L_SZ - 1));
  const float inv = 1.f / (sqrtf(var) + 1e-5f);
  float4 f = *(const float4*)&x[base];
  f.x = (f.x - mean) * inv; f.y = (f.y - mean) * inv;
  f.z = (f.z - mean) * inv; f.w = (f.w - mean) * inv;
  *(float4*)&xn[base] = f;
  u16x4 h; h[0] = f2bf(f.x); h[1] = f2bf(f.y); h[2] = f2bf(f.z); h[3] = f2bf(f.w);
  *(u16x4*)&xbf[base] = h;
}

// ---------------- Weight folds: W_proj@W_qkv (bf16 ^T + fp32 bias row) and W_out@W_head ----------------
__global__ void wcwf_kernel(const float* __restrict__ Wp, const float* __restrict__ bp,
                            const float* __restrict__ Wq, const float* __restrict__ bq,
                            const float* __restrict__ Wo, const float* __restrict__ bo,
                            const float* __restrict__ Wh, const float* __restrict__ bh,
                            float* __restrict__ Wcb, unsigned short* __restrict__ WqT,
                            unsigned short* __restrict__ WfT, float* __restrict__ bfp) {
  int idx = blockIdx.x * 256 + threadIdx.x;
  if (idx < 33 * 768) {
    int p = idx / 768, j = idx % 768;
    const float* arow = (p < 32) ? (Wp + p * 256) : bp;
    float acc = (p < 32) ? 0.f : bq[j];
    for (int d = 0; d < 256; ++d) acc += arow[d] * Wq[d * 768 + j];
    if (p < 32) WqT[j * 32 + p] = f2bf(acc);
    else Wcb[j] = acc;  // folded qkv bias row
  } else {
    int k = idx - 33 * 768;
    if (k < 8192) {
      int p = k >> 8, d = k & 255;
      float acc = 0.f;
      for (int e = 0; e < 256; ++e) acc += Wo[d * 256 + e] * Wh[e * 32 + p];
      WfT[p * 256 + d] = f2bf(acc);
    } else if (k < 8224) {
      int p = k - 8192;
      float acc = bh[p];
      for (int e = 0; e < 256; ++e) acc += bo[e] * Wh[e * 32 + p];
      bfp[p] = acc;
    }
  }
}

// ---------------- qkv MFMA GEMM; V emitted TRANSPOSED (Vt[b][d][t]) ----------------
__global__ __launch_bounds__(256) void gemm_qkv_mfma(const unsigned short* __restrict__ xbf,
                                                     const unsigned short* __restrict__ WqT,
                                                     const float* __restrict__ biasq,
                                                     unsigned short* __restrict__ Qb,
                                                     unsigned short* __restrict__ Kb,
                                                     unsigned short* __restrict__ Vt) {
  const int tid = threadIdx.x;
  const int w = tid >> 6, lane = tid & 63;
  const int lo = lane & 15, quad = lane >> 4;
  const int mbase = blockIdx.x * 128 + w * 32;
  // x fragments: A[m=lo][k=quad*8+j]  (also valid as B[k=quad*8+j][n=lo] of x^T)
  s16x8 af0 = *(const s16x8*)&xbf[(size_t)(mbase + lo) * 32 + quad * 8];
  s16x8 af1 = *(const s16x8*)&xbf[(size_t)(mbase + 16 + lo) * 32 + quad * 8];
  // ---- Q and K (row-major [t][d]) ----
#pragma unroll 4
  for (int nt = 0; nt < 32; ++nt) {
    s16x8 bf = *(const s16x8*)&WqT[(size_t)(nt * 16 + lo) * 32 + quad * 8];
    f32x4 c0 = {0.f, 0.f, 0.f, 0.f}, c1 = {0.f, 0.f, 0.f, 0.f};
    c0 = __builtin_amdgcn_mfma_f32_16x16x32_bf16(af0, bf, c0, 0, 0, 0);
    c1 = __builtin_amdgcn_mfma_f32_16x16x32_bf16(af1, bf, c1, 0, 0, 0);
    const int col = nt * 16 + lo;
    const float bi = biasq[col];
    unsigned short* dst; int ccl; float sc = 1.0f;
    if (col < 256) { dst = Qb; ccl = col; sc = 0.0625f; }
    else           { dst = Kb; ccl = col - 256; }
#pragma unroll
    for (int i = 0; i < 4; ++i) {
      dst[(size_t)(mbase + quad * 4 + i) * 256 + ccl]      = f2bf((c0[i] + bi) * sc);
      dst[(size_t)(mbase + 16 + quad * 4 + i) * 256 + ccl] = f2bf((c1[i] + bi) * sc);
    }
  }
  // ---- V transposed: Vt[d][t] = sum_p Wc[p][512+d] * x[t][p] ----
  const int bb = mbase >> 10, tt = mbase & 1023;
#pragma unroll 4
  for (int nt2 = 0; nt2 < 16; ++nt2) {
    s16x8 aw = *(const s16x8*)&WqT[(size_t)(512 + nt2 * 16 + lo) * 32 + quad * 8];
    f32x4 c0 = {0.f, 0.f, 0.f, 0.f}, c1 = {0.f, 0.f, 0.f, 0.f};
    c0 = __builtin_amdgcn_mfma_f32_16x16x32_bf16(aw, af0, c0, 0, 0, 0);  // D[d][t0+lo]
    c1 = __builtin_amdgcn_mfma_f32_16x16x32_bf16(aw, af1, c1, 0, 0, 0);  // D[d][t0+16+lo]
#pragma unroll
    for (int i = 0; i < 4; ++i) {
      const int d = nt2 * 16 + quad * 4 + i;
      const float bv = biasq[512 + d];
      Vt[((size_t)(bb * 256 + d)) * 1024 + tt + lo]      = f2bf(c0[i] + bv);
      Vt[((size_t)(bb * 256 + d)) * 1024 + tt + 16 + lo] = f2bf(c1[i] + bv);
    }
  }
}

// ---------------- Barrier-free flash attention + fused head-proj + MSE ----------------
// 512 blocks x 4 waves; each wave owns 16 q-rows, streams 32-key tiles from L2.
// No __syncthreads anywhere: per-wave LDS scratch only (P and O round-trips).
#define PST 44    // P row stride (shorts): quad rows land on distinct banks
#define OST 268   // O row stride (shorts): 2-way max on reads
__global__ __launch_bounds__(256, 3) void attn_kernel(const unsigned short* __restrict__ Qb,
                                                      const unsigned short* __restrict__ Kb,
                                                      const unsigned short* __restrict__ Vt,
                                                      const unsigned short* __restrict__ WfT,
                                                      const float* __restrict__ bfp,
                                                      const float* __restrict__ xn,
                                                      float* __restrict__ lsum) {
  const int i = blockIdx.x;
  const int b = ((i & 7) << 2) | (i >> 7);   // same-b blocks share an XCD (i%8 fixed)
  const int mp = (i >> 3) & 15;
  const int w = threadIdx.x >> 6, lane = threadIdx.x & 63;
  const int lo = lane & 15, quad = lane >> 4;
  const int qi = (15 - mp) * 4 + w;          // heavy-first; 4 consecutive qi per block

  __shared__ unsigned short SH[4][16 * OST];
  unsigned short* mysh = SH[w];

  const size_t kbase = (size_t)b * 1024;
  // Q fragments: A[m=lo][k=quad*8+j]
  s16x8 qf[8];
  const size_t qrow = (kbase + qi * 16 + lo) * 256;
#pragma unroll
  for (int kc = 0; kc < 8; ++kc) qf[kc] = *(const s16x8*)&Qb[qrow + kc * 32 + quad * 8];

  f32x4 O[16];
#pragma unroll
  for (int nt = 0; nt < 16; ++nt) O[nt] = (f32x4){0.f, 0.f, 0.f, 0.f};
  f32x4 Ol = {0.f, 0.f, 0.f, 0.f};
  float m_i[4] = {-1e30f, -1e30f, -1e30f, -1e30f};

  s16x8 ones;
#pragma unroll
  for (int j = 0; j < 8; ++j) ones[j] = (short)0x3F80;

  const int nk = (qi >> 1) + 1;
  for (int kt = 0; kt < nk; ++kt) {
    const int k0 = kt * 32;
    // ---- S = Q K^T (two 16-key n-tiles), K frags straight from L2 ----
    f32x4 s0 = {0.f, 0.f, 0.f, 0.f}, s1 = {0.f, 0.f, 0.f, 0.f};
#pragma unroll
    for (int kc = 0; kc < 8; ++kc) {
      s16x8 kf0 = *(const s16x8*)&Kb[(kbase + k0 + lo) * 256 + kc * 32 + quad * 8];
      s16x8 kf1 = *(const s16x8*)&Kb[(kbase + k0 + 16 + lo) * 256 + kc * 32 + quad * 8];
      s0 = __builtin_amdgcn_mfma_f32_16x16x32_bf16(qf[kc], kf0, s0, 0, 0, 0);
      s1 = __builtin_amdgcn_mfma_f32_16x16x32_bf16(qf[kc], kf1, s1, 0, 0, 0);
    }
    // ---- causal mask: only the final tile straddles ----
    if (kt == nk - 1) {
#pragma unroll
      for (int ii = 0; ii < 4; ++ii) {
        const int row = qi * 16 + quad * 4 + ii;
        if (k0 + lo > row) s0[ii] = -1e30f;
        if (k0 + 16 + lo > row) s1[ii] = -1e30f;
      }
    }
    // ---- online softmax; P -> per-wave LDS in bf16 ----
    float al[4];
#pragma unroll
    for (int ii = 0; ii < 4; ++ii) {
      float mx = fmaxf(s0[ii], s1[ii]);
      mx = fmaxf(mx, __shfl_xor(mx, 1));
      mx = fmaxf(mx, __shfl_xor(mx, 2));
      mx = fmaxf(mx, __shfl_xor(mx, 4));
      mx = fmaxf(mx, __shfl_xor(mx, 8));
      const float mnew = fmaxf(m_i[ii], mx);
      al[ii] = __expf(m_i[ii] - mnew);
      m_i[ii] = mnew;
      mysh[(quad * 4 + ii) * PST + lo]      = f2bf(__expf(s0[ii] - mnew));
      mysh[(quad * 4 + ii) * PST + 16 + lo] = f2bf(__expf(s1[ii] - mnew));
    }
    Ol[0] *= al[0]; Ol[1] *= al[1]; Ol[2] *= al[2]; Ol[3] *= al[3];
#pragma unroll
    for (int nt = 0; nt < 16; ++nt) {
      O[nt][0] *= al[0]; O[nt][1] *= al[1]; O[nt][2] *= al[2]; O[nt][3] *= al[3];
    }
    // ---- P back as A-frag (wave-local; compiler inserts lgkmcnt) ----
    s16x8 pf = *(const s16x8*)&mysh[lo * PST + quad * 8];
    Ol = __builtin_amdgcn_mfma_f32_16x16x32_bf16(pf, ones, Ol, 0, 0, 0);
#pragma unroll
    for (int nt = 0; nt < 16; ++nt) {
      s16x8 vf = *(const s16x8*)&Vt[((size_t)b * 256 + nt * 16 + lo) * 1024 + k0 + quad * 8];
      O[nt] = __builtin_amdgcn_mfma_f32_16x16x32_bf16(pf, vf, O[nt], 0, 0, 0);
    }
  }

  // ---- normalize, O -> LDS (A-layout), pred = O @ WfT^T + bfp, fused MSE ----
  float inv4[4];
#pragma unroll
  for (int ii = 0; ii < 4; ++ii) inv4[ii] = 1.f / Ol[ii];
#pragma unroll
  for (int nt = 0; nt < 16; ++nt)
#pragma unroll
    for (int ii = 0; ii < 4; ++ii)
      mysh[(quad * 4 + ii) * OST + nt * 16 + lo] = f2bf(O[nt][ii] * inv4[ii]);

  s16x8 af[8];
#pragma unroll
  for (int kc = 0; kc < 8; ++kc) af[kc] = *(const s16x8*)&mysh[lo * OST + kc * 32 + quad * 8];

  float lacc = 0.f;
#pragma unroll
  for (int nt = 0; nt < 2; ++nt) {
    f32x4 acc = {0.f, 0.f, 0.f, 0.f};
#pragma unroll
    for (int kc = 0; kc < 8; ++kc) {
      s16x8 bfr = *(const s16x8*)&WfT[(size_t)(nt * 16 + lo) * 256 + kc * 32 + quad * 8];
      acc = __builtin_amdgcn_mfma_f32_16x16x32_bf16(af[kc], bfr, acc, 0, 0, 0);
    }
    const float ba = bfp[nt * 16 + lo];
    const int p = nt * 16 + lo;
#pragma unroll
    for (int ii = 0; ii < 4; ++ii) {
      const int t = qi * 16 + quad * 4 + ii;
      if (t < 1023) {
        const float pr = acc[ii] + ba;
        const float tg = xn[(size_t)b * L_SZ + (t + 1) * 32 + p];
        const float d = pr - tg;
        lacc += d * d;
      }
    }
  }
#pragma unroll
  for (int off = 32; off >= 1; off >>= 1) lacc += __shfl_down(lacc, off);
  if (lane == 0) atomicAdd(lsum, lacc);
}

__global__ void finalize_kernel(const float* __restrict__ lsum, float* __restrict__ out) {
  out[0] = lsum[0] * (1.f / (float)(B_SZ * (T_SZ - 1) * PS_SZ));
}

extern "C" void kernel_launch(void* const* d_in, const int* in_sizes, int n_in,
                              void* d_out, int out_size, void* d_ws, size_t ws_size,
                              hipStream_t stream) {
  const float* x      = (const float*)d_in[0];
  const float* W_proj = (const float*)d_in[1];
  const float* b_proj = (const float*)d_in[2];
  const float* W_qkv  = (const float*)d_in[3];
  const float* b_qkv  = (const float*)d_in[4];
  const float* W_out  = (const float*)d_in[5];
  const float* b_out  = (const float*)d_in[6];
  const float* W_head = (const float*)d_in[7];
  const float* b_head = (const float*)d_in[8];
  float* out = (float*)d_out;

  char* ws = (char*)d_ws;
  float*          xn  = (float*)(ws);                           // [0,4M)
  unsigned short* xbf = (unsigned short*)(ws + (4ull << 20));   // [4M,6M)
  unsigned short* Qb  = (unsigned short*)(ws + (8ull << 20));   // 16MB
  unsigned short* Kb  = (unsigned short*)(ws + (24ull << 20));  // 16MB
  unsigned short* Vt  = (unsigned short*)(ws + (40ull << 20));  // 16MB
  char* tail = ws + (56ull << 20);
  float*          Wcb  = (float*)(tail);                        // 768 fp32 folded qkv bias
  unsigned short* WqT  = (unsigned short*)(tail + (128ull << 10));  // 768x32 bf16
  unsigned short* WfT  = (unsigned short*)(tail + (192ull << 10));  // 32x256 bf16
  float*          bfp  = (float*)(tail + (224ull << 10));       // 32 fp32
  float*          sget = (float*)(tail + (228ull << 10));       // 64 fp32 stats
  float*          lsum = (float*)(tail + (232ull << 10));       // 1 fp32

  hipMemsetAsync(sget, 0, 8192, stream);  // covers sget + lsum
  norm_stats<<<256, 256, 0, stream>>>(x, sget);
  norm_apply<<<1024, 256, 0, stream>>>(x, sget, xn, xbf);
  wcwf_kernel<<<132, 256, 0, stream>>>(W_proj, b_proj, W_qkv, b_qkv,
                                       W_out, b_out, W_head, b_head,
                                       Wcb, WqT, WfT, bfp);
  gemm_qkv_mfma<<<256, 256, 0, stream>>>(xbf, WqT, Wcb, Qb, Kb, Vt);
  attn_kernel<<<512, 256, 0, stream>>>(Qb, Kb, Vt, WfT, bfp, xn, lsum);
  finalize_kernel<<<1, 1, 0, stream>>>(lsum, out);
}

// Round 5
// 263.438 us; speedup vs baseline: 1.3900x; 1.3900x over previous
//
#include <hip/hip_runtime.h>
#include <math.h>

#define B_SZ 32
#define L_SZ 32768
#define T_SZ 1024
#define PS_SZ 32
#define D_SZ 256

typedef float f32x4 __attribute__((ext_vector_type(4)));
typedef short s16x8 __attribute__((ext_vector_type(8)));
typedef unsigned short u16x8 __attribute__((ext_vector_type(8)));
typedef unsigned short u16x4 __attribute__((ext_vector_type(4)));

__device__ __forceinline__ unsigned short f2bf(float f) {
  union { float f; unsigned int u; } v; v.f = f;
  unsigned int r = v.u + 0x7FFFu + ((v.u >> 16) & 1u);
  return (unsigned short)(r >> 16);
}

// ---------------- InstanceNorm pass 1: partial sums (8 blocks per row) ----------------
__global__ __launch_bounds__(256) void norm_stats(const float* __restrict__ x,
                                                  float* __restrict__ sget) {
  const int b = blockIdx.x >> 3;
  const float* p = x + (size_t)b * L_SZ + (size_t)(blockIdx.x & 7) * 4096;
  float s = 0.f, ss = 0.f;
#pragma unroll
  for (int i = 0; i < 4; ++i) {
    float4 f = ((const float4*)p)[threadIdx.x + i * 256];
    s += f.x + f.y + f.z + f.w;
    ss += f.x * f.x + f.y * f.y + f.z * f.z + f.w * f.w;
  }
#pragma unroll
  for (int off = 32; off >= 1; off >>= 1) {
    s += __shfl_down(s, off);
    ss += __shfl_down(ss, off);
  }
  __shared__ float rs[4], rss[4];
  const int wid = threadIdx.x >> 6, lane = threadIdx.x & 63;
  if (lane == 0) { rs[wid] = s; rss[wid] = ss; }
  __syncthreads();
  if (threadIdx.x == 0) {
    atomicAdd(&sget[b * 2],     rs[0] + rs[1] + rs[2] + rs[3]);
    atomicAdd(&sget[b * 2 + 1], rss[0] + rss[1] + rss[2] + rss[3]);
  }
}

// ---------------- Weight folds: W_proj@W_qkv (bf16 ^T + fp32 bias) and W_out@W_head ----------------
__global__ void wcwf_kernel(const float* __restrict__ Wp, const float* __restrict__ bp,
                            const float* __restrict__ Wq, const float* __restrict__ bq,
                            const float* __restrict__ Wo, const float* __restrict__ bo,
                            const float* __restrict__ Wh, const float* __restrict__ bh,
                            float* __restrict__ Wcb, unsigned short* __restrict__ WqT,
                            unsigned short* __restrict__ WfT, float* __restrict__ bfp) {
  int idx = blockIdx.x * 256 + threadIdx.x;
  if (idx < 33 * 768) {
    int p = idx / 768, j = idx % 768;
    const float* arow = (p < 32) ? (Wp + p * 256) : bp;
    float acc = (p < 32) ? 0.f : bq[j];
    for (int d = 0; d < 256; ++d) acc += arow[d] * Wq[d * 768 + j];
    if (p < 32) WqT[j * 32 + p] = f2bf(acc);
    else Wcb[j] = acc;  // folded qkv bias row
  } else {
    int k = idx - 33 * 768;
    if (k < 8192) {
      int p = k >> 8, d = k & 255;
      float acc = 0.f;
      for (int e = 0; e < 256; ++e) acc += Wo[d * 256 + e] * Wh[e * 32 + p];
      WfT[p * 256 + d] = f2bf(acc);
    } else if (k < 8224) {
      int p = k - 8192;
      float acc = bh[p];
      for (int e = 0; e < 256; ++e) acc += bo[e] * Wh[e * 32 + p];
      bfp[p] = acc;
    }
  }
}

// ---------------- qkv MFMA GEMM with fused normalization; V emitted TRANSPOSED ----------------
__global__ __launch_bounds__(256) void gemm_qkv_mfma(const float* __restrict__ x,
                                                     const float* __restrict__ sget,
                                                     const unsigned short* __restrict__ WqT,
                                                     const float* __restrict__ biasq,
                                                     unsigned short* __restrict__ Qb,
                                                     unsigned short* __restrict__ Kb,
                                                     unsigned short* __restrict__ Vt) {
  const int tid = threadIdx.x;
  const int w = tid >> 6, lane = tid & 63;
  const int lo = lane & 15, quad = lane >> 4;
  const int mbase = blockIdx.x * 128 + w * 32;
  const int b = mbase >> 10;
  const float S = sget[b * 2], SS = sget[b * 2 + 1];
  const float mean = S * (1.f / (float)L_SZ);
  const float var = (SS - S * mean) * (1.f / (float)(L_SZ - 1));
  const float inv = 1.f / (sqrtf(var) + 1e-5f);
  // x fragments (normalized inline): A[m=lo][k=quad*8+j]
  s16x8 af0, af1;
  {
    float4 a = *(const float4*)&x[(size_t)(mbase + lo) * 32 + quad * 8];
    float4 c = *(const float4*)&x[(size_t)(mbase + lo) * 32 + quad * 8 + 4];
    af0[0] = (short)f2bf((a.x - mean) * inv); af0[1] = (short)f2bf((a.y - mean) * inv);
    af0[2] = (short)f2bf((a.z - mean) * inv); af0[3] = (short)f2bf((a.w - mean) * inv);
    af0[4] = (short)f2bf((c.x - mean) * inv); af0[5] = (short)f2bf((c.y - mean) * inv);
    af0[6] = (short)f2bf((c.z - mean) * inv); af0[7] = (short)f2bf((c.w - mean) * inv);
    float4 d = *(const float4*)&x[(size_t)(mbase + 16 + lo) * 32 + quad * 8];
    float4 e = *(const float4*)&x[(size_t)(mbase + 16 + lo) * 32 + quad * 8 + 4];
    af1[0] = (short)f2bf((d.x - mean) * inv); af1[1] = (short)f2bf((d.y - mean) * inv);
    af1[2] = (short)f2bf((d.z - mean) * inv); af1[3] = (short)f2bf((d.w - mean) * inv);
    af1[4] = (short)f2bf((e.x - mean) * inv); af1[5] = (short)f2bf((e.y - mean) * inv);
    af1[6] = (short)f2bf((e.z - mean) * inv); af1[7] = (short)f2bf((e.w - mean) * inv);
  }
  // ---- Q and K (row-major [t][d]) ----
#pragma unroll 4
  for (int nt = 0; nt < 32; ++nt) {
    s16x8 bf = *(const s16x8*)&WqT[(size_t)(nt * 16 + lo) * 32 + quad * 8];
    f32x4 c0 = {0.f, 0.f, 0.f, 0.f}, c1 = {0.f, 0.f, 0.f, 0.f};
    c0 = __builtin_amdgcn_mfma_f32_16x16x32_bf16(af0, bf, c0, 0, 0, 0);
    c1 = __builtin_amdgcn_mfma_f32_16x16x32_bf16(af1, bf, c1, 0, 0, 0);
    const int col = nt * 16 + lo;
    const float bi = biasq[col];
    unsigned short* dst; int ccl; float sc = 1.0f;
    if (col < 256) { dst = Qb; ccl = col; sc = 0.0625f; }
    else           { dst = Kb; ccl = col - 256; }
#pragma unroll
    for (int i = 0; i < 4; ++i) {
      dst[(size_t)(mbase + quad * 4 + i) * 256 + ccl]      = f2bf((c0[i] + bi) * sc);
      dst[(size_t)(mbase + 16 + quad * 4 + i) * 256 + ccl] = f2bf((c1[i] + bi) * sc);
    }
  }
  // ---- V transposed: Vt[d][t] (verified in R4) ----
  const int bb = mbase >> 10, tt = mbase & 1023;
#pragma unroll 4
  for (int nt2 = 0; nt2 < 16; ++nt2) {
    s16x8 aw = *(const s16x8*)&WqT[(size_t)(512 + nt2 * 16 + lo) * 32 + quad * 8];
    f32x4 c0 = {0.f, 0.f, 0.f, 0.f}, c1 = {0.f, 0.f, 0.f, 0.f};
    c0 = __builtin_amdgcn_mfma_f32_16x16x32_bf16(aw, af0, c0, 0, 0, 0);
    c1 = __builtin_amdgcn_mfma_f32_16x16x32_bf16(aw, af1, c1, 0, 0, 0);
#pragma unroll
    for (int i = 0; i < 4; ++i) {
      const int d = nt2 * 16 + quad * 4 + i;
      const float bv = biasq[512 + d];
      Vt[((size_t)(bb * 256 + d)) * 1024 + tt + lo]      = f2bf(c0[i] + bv);
      Vt[((size_t)(bb * 256 + d)) * 1024 + tt + 16 + lo] = f2bf(c1[i] + bv);
    }
  }
}

// ---------------- In-block split-K flash attention + fused head-proj + MSE ----------------
// 2048 blocks = (b, 16-row q-tile), heavy-first, XCD-grouped by b.
// 4 waves split the key range; fp32 partial combine in LDS; wave 0 does epilogue.
#define PST 40
__global__ __launch_bounds__(256) void attn_kernel(const unsigned short* __restrict__ Qb,
                                                   const unsigned short* __restrict__ Kb,
                                                   const unsigned short* __restrict__ Vt,
                                                   const unsigned short* __restrict__ WfT,
                                                   const float* __restrict__ bfp,
                                                   const float* __restrict__ x,
                                                   const float* __restrict__ sget,
                                                   float* __restrict__ lsum) {
  const int g = blockIdx.x;
  const int j = g >> 3;
  const int b = (g & 7) + ((j & 3) << 3);   // XCD id (g%8) pinned to b%8
  const int qi = 63 - (j >> 2);             // heavy-first
  const int w = threadIdx.x >> 6, lane = threadIdx.x & 63;
  const int lo = lane & 15, quad = lane >> 4;

  __shared__ float OLp[3][256][20];         // fp32 partials of waves 1..3, [col][row]
  __shared__ unsigned short Pst[4][16][PST];
  __shared__ float ml[4][16][2];            // {m, l} per wave per row
  __shared__ unsigned short OL[16][264];    // final O bf16 for epilogue A-frags

  const size_t kbase = (size_t)b << 10;
  // Q fragments: A[m=lo][k=quad*8+jj]
  s16x8 qf[8];
  const size_t qrow = (kbase + qi * 16 + lo) * 256;
#pragma unroll
  for (int kc = 0; kc < 8; ++kc) qf[kc] = *(const s16x8*)&Qb[qrow + kc * 32 + quad * 8];

  f32x4 O[16];
#pragma unroll
  for (int nt = 0; nt < 16; ++nt) O[nt] = (f32x4){0.f, 0.f, 0.f, 0.f};
  f32x4 Ol = {0.f, 0.f, 0.f, 0.f};
  float m_i[4] = {-1e30f, -1e30f, -1e30f, -1e30f};

  s16x8 ones;
#pragma unroll
  for (int jj = 0; jj < 8; ++jj) ones[jj] = (short)0x3F80;

  const int nk = (qi >> 1) + 1;
  const int c = (nk + 3) >> 2;
  const int kts = w * c;
  const int kte0 = kts + c;
  const int kte = kte0 < nk ? kte0 : nk;
  unsigned short* myp = &Pst[w][0][0];

  for (int kt = kts; kt < kte; ++kt) {
    const int k0 = kt * 32;
    // ---- S = Q K^T (two 16-key n-tiles), K frags from L2 ----
    f32x4 s0 = {0.f, 0.f, 0.f, 0.f}, s1 = {0.f, 0.f, 0.f, 0.f};
#pragma unroll
    for (int kc = 0; kc < 8; ++kc) {
      s16x8 kf0 = *(const s16x8*)&Kb[(kbase + k0 + lo) * 256 + kc * 32 + quad * 8];
      s16x8 kf1 = *(const s16x8*)&Kb[(kbase + k0 + 16 + lo) * 256 + kc * 32 + quad * 8];
      s0 = __builtin_amdgcn_mfma_f32_16x16x32_bf16(qf[kc], kf0, s0, 0, 0, 0);
      s1 = __builtin_amdgcn_mfma_f32_16x16x32_bf16(qf[kc], kf1, s1, 0, 0, 0);
    }
    if (kt == nk - 1) {  // only the final global tile straddles the diagonal
#pragma unroll
      for (int ii = 0; ii < 4; ++ii) {
        const int row = qi * 16 + quad * 4 + ii;
        if (k0 + lo > row) s0[ii] = -1e30f;
        if (k0 + 16 + lo > row) s1[ii] = -1e30f;
      }
    }
    float al[4];
#pragma unroll
    for (int ii = 0; ii < 4; ++ii) {
      float mx = fmaxf(s0[ii], s1[ii]);
      mx = fmaxf(mx, __shfl_xor(mx, 1));
      mx = fmaxf(mx, __shfl_xor(mx, 2));
      mx = fmaxf(mx, __shfl_xor(mx, 4));
      mx = fmaxf(mx, __shfl_xor(mx, 8));
      const float mnew = fmaxf(m_i[ii], mx);
      al[ii] = __expf(m_i[ii] - mnew);
      m_i[ii] = mnew;
      myp[(quad * 4 + ii) * PST + lo]      = f2bf(__expf(s0[ii] - mnew));
      myp[(quad * 4 + ii) * PST + 16 + lo] = f2bf(__expf(s1[ii] - mnew));
    }
    Ol[0] *= al[0]; Ol[1] *= al[1]; Ol[2] *= al[2]; Ol[3] *= al[3];
#pragma unroll
    for (int nt = 0; nt < 16; ++nt) {
      O[nt][0] *= al[0]; O[nt][1] *= al[1]; O[nt][2] *= al[2]; O[nt][3] *= al[3];
    }
    s16x8 pf = *(const s16x8*)&myp[lo * PST + quad * 8];
    Ol = __builtin_amdgcn_mfma_f32_16x16x32_bf16(pf, ones, Ol, 0, 0, 0);
#pragma unroll
    for (int nt = 0; nt < 16; ++nt) {
      s16x8 vf = *(const s16x8*)&Vt[((size_t)b * 256 + nt * 16 + lo) * 1024 + k0 + quad * 8];
      O[nt] = __builtin_amdgcn_mfma_f32_16x16x32_bf16(pf, vf, O[nt], 0, 0, 0);
    }
  }

  // ---- publish partials ----
  if (w != 0) {
#pragma unroll
    for (int nt = 0; nt < 16; ++nt)
#pragma unroll
      for (int ii = 0; ii < 4; ++ii)
        OLp[w - 1][nt * 16 + lo][quad * 4 + ii] = O[nt][ii];
  }
  if (lo == 0) {
#pragma unroll
    for (int ii = 0; ii < 4; ++ii) {
      ml[w][quad * 4 + ii][0] = m_i[ii];
      ml[w][quad * 4 + ii][1] = Ol[ii];
    }
  }
  __syncthreads();          // the only barrier; waves 1..3 exit after it
  if (w != 0) return;

  // ---- wave 0: merge partials ----
  float cf1[4], cf2[4], cf3[4], linv[4];
#pragma unroll
  for (int ii = 0; ii < 4; ++ii) {
    const int r = quad * 4 + ii;
    const float m0 = m_i[ii];
    const float m1 = ml[1][r][0], m2 = ml[2][r][0], m3 = ml[3][r][0];
    const float M = fmaxf(fmaxf(m0, m1), fmaxf(m2, m3));
    const float c0 = __expf(m0 - M);
    cf1[ii] = __expf(m1 - M); cf2[ii] = __expf(m2 - M); cf3[ii] = __expf(m3 - M);
    const float lf = c0 * Ol[ii] + cf1[ii] * ml[1][r][1] + cf2[ii] * ml[2][r][1] +
                     cf3[ii] * ml[3][r][1];
    linv[ii] = c0 / lf;  // fold c0 into the final normalization
    cf1[ii] /= c0; cf2[ii] /= c0; cf3[ii] /= c0;
  }
#pragma unroll
  for (int nt = 0; nt < 16; ++nt) {
    f32x4 p1 = *(const f32x4*)&OLp[0][nt * 16 + lo][quad * 4];
    f32x4 p2 = *(const f32x4*)&OLp[1][nt * 16 + lo][quad * 4];
    f32x4 p3 = *(const f32x4*)&OLp[2][nt * 16 + lo][quad * 4];
#pragma unroll
    for (int ii = 0; ii < 4; ++ii) {
      const float of = (O[nt][ii] + cf1[ii] * p1[ii] + cf2[ii] * p2[ii] + cf3[ii] * p3[ii]) *
                       linv[ii];
      OL[quad * 4 + ii][nt * 16 + lo] = f2bf(of);
    }
  }

  // ---- pred = O @ WfT^T + bfp ; fused next-patch MSE (targets normalized inline) ----
  const float S = sget[b * 2], SS = sget[b * 2 + 1];
  const float mean = S * (1.f / (float)L_SZ);
  const float var = (SS - S * mean) * (1.f / (float)(L_SZ - 1));
  const float invb = 1.f / (sqrtf(var) + 1e-5f);

  s16x8 af[8];
#pragma unroll
  for (int kc = 0; kc < 8; ++kc) af[kc] = *(const s16x8*)&OL[lo][kc * 32 + quad * 8];

  float lacc = 0.f;
#pragma unroll
  for (int nt = 0; nt < 2; ++nt) {
    f32x4 acc = {0.f, 0.f, 0.f, 0.f};
#pragma unroll
    for (int kc = 0; kc < 8; ++kc) {
      s16x8 bfr = *(const s16x8*)&WfT[(size_t)(nt * 16 + lo) * 256 + kc * 32 + quad * 8];
      acc = __builtin_amdgcn_mfma_f32_16x16x32_bf16(af[kc], bfr, acc, 0, 0, 0);
    }
    const float ba = bfp[nt * 16 + lo];
    const int p = nt * 16 + lo;
#pragma unroll
    for (int ii = 0; ii < 4; ++ii) {
      const int t = qi * 16 + quad * 4 + ii;
      if (t < 1023) {
        const float pr = acc[ii] + ba;
        const float tg = (x[(size_t)b * L_SZ + (t + 1) * 32 + p] - mean) * invb;
        const float d = pr - tg;
        lacc += d * d;
      }
    }
  }
#pragma unroll
  for (int off = 32; off >= 1; off >>= 1) lacc += __shfl_down(lacc, off);
  if (lane == 0) atomicAdd(lsum, lacc);
}

__global__ void finalize_kernel(const float* __restrict__ lsum, float* __restrict__ out) {
  out[0] = lsum[0] * (1.f / (float)(B_SZ * (T_SZ - 1) * PS_SZ));
}

extern "C" void kernel_launch(void* const* d_in, const int* in_sizes, int n_in,
                              void* d_out, int out_size, void* d_ws, size_t ws_size,
                              hipStream_t stream) {
  const float* x      = (const float*)d_in[0];
  const float* W_proj = (const float*)d_in[1];
  const float* b_proj = (const float*)d_in[2];
  const float* W_qkv  = (const float*)d_in[3];
  const float* b_qkv  = (const float*)d_in[4];
  const float* W_out  = (const float*)d_in[5];
  const float* b_out  = (const float*)d_in[6];
  const float* W_head = (const float*)d_in[7];
  const float* b_head = (const float*)d_in[8];
  float* out = (float*)d_out;

  char* ws = (char*)d_ws;
  unsigned short* Qb = (unsigned short*)(ws);                  // 16MB
  unsigned short* Kb = (unsigned short*)(ws + (16ull << 20));  // 16MB
  unsigned short* Vt = (unsigned short*)(ws + (32ull << 20));  // 16MB
  char* tail = ws + (48ull << 20);
  float*          Wcb  = (float*)(tail);                          // 768 fp32 folded qkv bias
  unsigned short* WqT  = (unsigned short*)(tail + (4ull << 10));  // 768x32 bf16
  unsigned short* WfT  = (unsigned short*)(tail + (64ull << 10)); // 32x256 bf16
  float*          bfp  = (float*)(tail + (96ull << 10));          // 32 fp32
  float*          sget = (float*)(tail + (100ull << 10));         // 64 fp32 stats
  float*          lsum = (float*)(tail + (100ull << 10) + 256);   // 1 fp32

  hipMemsetAsync(sget, 0, 512, stream);  // sget + lsum
  norm_stats<<<256, 256, 0, stream>>>(x, sget);
  wcwf_kernel<<<132, 256, 0, stream>>>(W_proj, b_proj, W_qkv, b_qkv,
                                       W_out, b_out, W_head, b_head,
                                       Wcb, WqT, WfT, bfp);
  gemm_qkv_mfma<<<256, 256, 0, stream>>>(x, sget, WqT, Wcb, Qb, Kb, Vt);
  attn_kernel<<<2048, 256, 0, stream>>>(Qb, Kb, Vt, WfT, bfp, x, sget, lsum);
  finalize_kernel<<<1, 1, 0, stream>>>(lsum, out);
}

// Round 7
// 165.158 us; speedup vs baseline: 2.2171x; 1.5951x over previous
//
#include <hip/hip_runtime.h>
#include <math.h>

#define B_SZ 32
#define L_SZ 32768
#define T_SZ 1024
#define PS_SZ 32
#define D_SZ 256
#define SM_M 10.0f   // static softmax max-shift; scores ~N(0,1), max << 10

typedef float f32x4 __attribute__((ext_vector_type(4)));
typedef short s16x8 __attribute__((ext_vector_type(8)));
typedef unsigned short u16x8 __attribute__((ext_vector_type(8)));
typedef unsigned short u16x4 __attribute__((ext_vector_type(4)));

__device__ __forceinline__ unsigned short f2bf(float f) {
  union { float f; unsigned int u; } v; v.f = f;
  unsigned int r = v.u + 0x7FFFu + ((v.u >> 16) & 1u);
  return (unsigned short)(r >> 16);
}

// async global->LDS 16B: per-lane global addr, wave-uniform LDS base (+lane*16 by HW)
__device__ __forceinline__ void g2l16(const unsigned short* g, unsigned short* l) {
  __builtin_amdgcn_global_load_lds(
      (const __attribute__((address_space(1))) unsigned int*)g,
      (__attribute__((address_space(3))) unsigned int*)l, 16, 0, 0);
}

// ---------------- prep: norm partial sums (blocks 0..255) + weight folds (256..387) ----------------
__global__ __launch_bounds__(256) void prep_kernel(const float* __restrict__ x,
                                                   float* __restrict__ sget,
                                                   const float* __restrict__ Wp,
                                                   const float* __restrict__ bp,
                                                   const float* __restrict__ Wq,
                                                   const float* __restrict__ bq,
                                                   const float* __restrict__ Wo,
                                                   const float* __restrict__ bo,
                                                   const float* __restrict__ Wh,
                                                   const float* __restrict__ bh,
                                                   float* __restrict__ Wcb,
                                                   unsigned short* __restrict__ WqT,
                                                   unsigned short* __restrict__ WfT,
                                                   float* __restrict__ bfp) {
  if (blockIdx.x < 256) {
    const int b = blockIdx.x >> 3;
    const float* p = x + (size_t)b * L_SZ + (size_t)(blockIdx.x & 7) * 4096;
    float s = 0.f, ss = 0.f;
#pragma unroll
    for (int i = 0; i < 4; ++i) {
      float4 f = ((const float4*)p)[threadIdx.x + i * 256];
      s += f.x + f.y + f.z + f.w;
      ss += f.x * f.x + f.y * f.y + f.z * f.z + f.w * f.w;
    }
#pragma unroll
    for (int off = 32; off >= 1; off >>= 1) {
      s += __shfl_down(s, off);
      ss += __shfl_down(ss, off);
    }
    __shared__ float rs[4], rss[4];
    const int wid = threadIdx.x >> 6, lane = threadIdx.x & 63;
    if (lane == 0) { rs[wid] = s; rss[wid] = ss; }
    __syncthreads();
    if (threadIdx.x == 0) {
      atomicAdd(&sget[b * 2],     rs[0] + rs[1] + rs[2] + rs[3]);
      atomicAdd(&sget[b * 2 + 1], rss[0] + rss[1] + rss[2] + rss[3]);
    }
  } else {
    int idx = (blockIdx.x - 256) * 256 + threadIdx.x;
    if (idx < 33 * 768) {
      int p = idx / 768, j = idx % 768;
      const float* arow = (p < 32) ? (Wp + p * 256) : bp;
      float acc = (p < 32) ? 0.f : bq[j];
      for (int d = 0; d < 256; ++d) acc += arow[d] * Wq[d * 768 + j];
      if (p < 32) WqT[j * 32 + p] = f2bf(acc);
      else Wcb[j] = acc;
    } else {
      int k = idx - 33 * 768;
      if (k < 8192) {
        int p = k >> 8, d = k & 255;
        float acc = 0.f;
        for (int e = 0; e < 256; ++e) acc += Wo[d * 256 + e] * Wh[e * 32 + p];
        WfT[p * 256 + d] = f2bf(acc);
      } else if (k < 8224) {
        int p = k - 8192;
        float acc = bh[p];
        for (int e = 0; e < 256; ++e) acc += bo[e] * Wh[e * 32 + p];
        bfp[p] = acc;
      }
    }
  }
}

// ---------------- qkv MFMA GEMM, fused norm; LDS-staged coalesced stores ----------------
// Qb/Kb row-major [b*1024+t][256]; V in kt-tiled transposed layout Vtt[(b*32+kt)*256+d][32].
__global__ __launch_bounds__(256) void gemm_qkv_mfma(const float* __restrict__ x,
                                                     const float* __restrict__ sget,
                                                     const unsigned short* __restrict__ WqT,
                                                     const float* __restrict__ biasq,
                                                     unsigned short* __restrict__ Qb,
                                                     unsigned short* __restrict__ Kb,
                                                     unsigned short* __restrict__ Vtt) {
  __shared__ unsigned short T4[4][8448];   // per-wave staging tile
  const int tid = threadIdx.x;
  const int w = tid >> 6, lane = tid & 63;
  const int lo = lane & 15, quad = lane >> 4;
  unsigned short* Tw = T4[w];
  const int mbase = blockIdx.x * 128 + w * 32;
  const int b = mbase >> 10;
  const float S = sget[b * 2], SS = sget[b * 2 + 1];
  const float mean = S * (1.f / (float)L_SZ);
  const float var = (SS - S * mean) * (1.f / (float)(L_SZ - 1));
  const float inv = 1.f / (sqrtf(var) + 1e-5f);
  // x fragments, normalized inline: A[m=lo][k=quad*8+j]
  s16x8 af0, af1;
  {
    float4 a = *(const float4*)&x[(size_t)(mbase + lo) * 32 + quad * 8];
    float4 c = *(const float4*)&x[(size_t)(mbase + lo) * 32 + quad * 8 + 4];
    af0[0] = (short)f2bf((a.x - mean) * inv); af0[1] = (short)f2bf((a.y - mean) * inv);
    af0[2] = (short)f2bf((a.z - mean) * inv); af0[3] = (short)f2bf((a.w - mean) * inv);
    af0[4] = (short)f2bf((c.x - mean) * inv); af0[5] = (short)f2bf((c.y - mean) * inv);
    af0[6] = (short)f2bf((c.z - mean) * inv); af0[7] = (short)f2bf((c.w - mean) * inv);
    float4 d = *(const float4*)&x[(size_t)(mbase + 16 + lo) * 32 + quad * 8];
    float4 e = *(const float4*)&x[(size_t)(mbase + 16 + lo) * 32 + quad * 8 + 4];
    af1[0] = (short)f2bf((d.x - mean) * inv); af1[1] = (short)f2bf((d.y - mean) * inv);
    af1[2] = (short)f2bf((d.z - mean) * inv); af1[3] = (short)f2bf((d.w - mean) * inv);
    af1[4] = (short)f2bf((e.x - mean) * inv); af1[5] = (short)f2bf((e.y - mean) * inv);
    af1[6] = (short)f2bf((e.z - mean) * inv); af1[7] = (short)f2bf((e.w - mean) * inv);
  }
  // ---- Q phase (cols 0..255, pre-scaled 1/16) ----
#pragma unroll 4
  for (int nt = 0; nt < 16; ++nt) {
    s16x8 bf = *(const s16x8*)&WqT[(size_t)(nt * 16 + lo) * 32 + quad * 8];
    f32x4 c0 = {0.f, 0.f, 0.f, 0.f}, c1 = {0.f, 0.f, 0.f, 0.f};
    c0 = __builtin_amdgcn_mfma_f32_16x16x32_bf16(af0, bf, c0, 0, 0, 0);
    c1 = __builtin_amdgcn_mfma_f32_16x16x32_bf16(af1, bf, c1, 0, 0, 0);
    const int col = nt * 16 + lo;
    const float bi = biasq[col];
#pragma unroll
    for (int i = 0; i < 4; ++i) {
      Tw[(quad * 4 + i) * 264 + col]      = f2bf((c0[i] + bi) * 0.0625f);
      Tw[(16 + quad * 4 + i) * 264 + col] = f2bf((c1[i] + bi) * 0.0625f);
    }
  }
#pragma unroll
  for (int it = 0; it < 16; ++it) {
    const int gsub = it * 64 + lane;
    const int row = gsub >> 5, c16 = gsub & 31;
    *(u16x8*)&Qb[(size_t)(mbase + row) * 256 + c16 * 8] =
        *(const u16x8*)&Tw[row * 264 + c16 * 8];
  }
  // ---- K phase (cols 256..511) ----
#pragma unroll 4
  for (int nt = 0; nt < 16; ++nt) {
    s16x8 bf = *(const s16x8*)&WqT[(size_t)(256 + nt * 16 + lo) * 32 + quad * 8];
    f32x4 c0 = {0.f, 0.f, 0.f, 0.f}, c1 = {0.f, 0.f, 0.f, 0.f};
    c0 = __builtin_amdgcn_mfma_f32_16x16x32_bf16(af0, bf, c0, 0, 0, 0);
    c1 = __builtin_amdgcn_mfma_f32_16x16x32_bf16(af1, bf, c1, 0, 0, 0);
    const int col = nt * 16 + lo;
    const float bi = biasq[256 + col];
#pragma unroll
    for (int i = 0; i < 4; ++i) {
      Tw[(quad * 4 + i) * 264 + col]      = f2bf(c0[i] + bi);
      Tw[(16 + quad * 4 + i) * 264 + col] = f2bf(c1[i] + bi);
    }
  }
#pragma unroll
  for (int it = 0; it < 16; ++it) {
    const int gsub = it * 64 + lane;
    const int row = gsub >> 5, c16 = gsub & 31;
    *(u16x8*)&Kb[(size_t)(mbase + row) * 256 + c16 * 8] =
        *(const u16x8*)&Tw[row * 264 + c16 * 8];
  }
  // ---- V phase, transposed: Vtile[d][t_local] (wave's 32 t = one kt tile) ----
#pragma unroll 4
  for (int nt2 = 0; nt2 < 16; ++nt2) {
    s16x8 aw = *(const s16x8*)&WqT[(size_t)(512 + nt2 * 16 + lo) * 32 + quad * 8];
    f32x4 c0 = {0.f, 0.f, 0.f, 0.f}, c1 = {0.f, 0.f, 0.f, 0.f};
    c0 = __builtin_amdgcn_mfma_f32_16x16x32_bf16(aw, af0, c0, 0, 0, 0);  // D[d][t0+lo]
    c1 = __builtin_amdgcn_mfma_f32_16x16x32_bf16(aw, af1, c1, 0, 0, 0);  // D[d][t0+16+lo]
#pragma unroll
    for (int i = 0; i < 4; ++i) {
      const int d = nt2 * 16 + quad * 4 + i;
      const float bv = biasq[512 + d];
      Tw[d * 32 + lo]      = f2bf(c0[i] + bv);
      Tw[d * 32 + 16 + lo] = f2bf(c1[i] + bv);
    }
  }
  {
    const int ktq = (mbase >> 5) & 31;
    const size_t vb = ((size_t)b * 32 + ktq) * 8192;
    // FIX (R6 bug): tile is 256*32 = 8192 shorts -> 16 iterations, not 8.
#pragma unroll
    for (int it = 0; it < 16; ++it) {
      const int gsub = it * 64 + lane;
      *(u16x8*)&Vtt[vb + gsub * 8] = *(const u16x8*)&Tw[gsub * 8];
    }
  }
}

// ---------------- Flash attention (static-M softmax) + fused head-proj + MSE ----------------
// 512 blocks = (b, 64-row q-tile), heavy-first, XCD-pinned by b. 4 waves x 16 q-rows
// share LDS-staged K/V 32-key tiles (global_load_lds, XOR-swizzled images).
__global__ __launch_bounds__(256) void attn_kernel(const unsigned short* __restrict__ Qb,
                                                   const unsigned short* __restrict__ Kb,
                                                   const unsigned short* __restrict__ Vtt,
                                                   const unsigned short* __restrict__ WfT,
                                                   const float* __restrict__ bfp,
                                                   const float* __restrict__ x,
                                                   const float* __restrict__ sget,
                                                   float* __restrict__ lsum) {
  __shared__ unsigned short SH[18944];  // Ks [0,8192) Vs [8192,16384) P [16384,18944); OL overlays
  const int g = blockIdx.x;
  const int j = g >> 3;
  const int b = (g & 7) * 4 + (j & 3);  // XCD id (g%8) pinned per b
  const int qt = 15 - (j >> 2);         // heavy-first
  const int tid = threadIdx.x;
  const int w = tid >> 6, lane = tid & 63;
  const int lo = lane & 15, quad = lane >> 4;
  const int lo7 = lo & 7;
  const int qr0 = qt * 64 + w * 16;

  const size_t kbase = (size_t)b << 10;
  s16x8 qf[8];
  const size_t qrow = (kbase + qr0 + lo) * 256;
#pragma unroll
  for (int kc = 0; kc < 8; ++kc) qf[kc] = *(const s16x8*)&Qb[qrow + kc * 32 + quad * 8];

  f32x4 O[16];
#pragma unroll
  for (int nt = 0; nt < 16; ++nt) O[nt] = (f32x4){0.f, 0.f, 0.f, 0.f};
  f32x4 Ol = {0.f, 0.f, 0.f, 0.f};

  s16x8 ones;
#pragma unroll
  for (int jj = 0; jj < 8; ++jj) ones[jj] = (short)0x3F80;

  unsigned short* myp = &SH[16384 + w * 640];
  const int nk = 2 * (qt + 1);

  for (int kt = 0; kt < nk; ++kt) {
    const int k0 = kt * 32;
    __syncthreads();  // everyone done reading prev tile
    // stage K image: Ks[key][c16'] with c16' low3 = c16 ^ (key&7)
#pragma unroll
    for (int it = 0; it < 4; ++it) {
      const int s = it * 256 + tid;
      const int key = s >> 5, c16p = s & 31;
      const int c16 = (c16p & 24) | ((c16p & 7) ^ (key & 7));
      g2l16(&Kb[((kbase + k0 + key) << 8) + (c16 << 3)], &SH[(it * 256 + w * 64) * 8]);
    }
    // stage V image: Vs[d][c'] with c' = c ^ ((d>>1)&3)
    const size_t vb = ((size_t)b * 32 + kt) * 8192;
#pragma unroll
    for (int it = 0; it < 4; ++it) {
      const int s = it * 256 + tid;
      const int d = s >> 2, cp = s & 3;
      const int c = cp ^ ((d >> 1) & 3);
      g2l16(&Vtt[vb + ((d << 2) + c) * 8], &SH[8192 + (it * 256 + w * 64) * 8]);
    }
    __syncthreads();  // loads drained, tiles visible

    if (k0 <= qr0 + 15) {  // wave-uniform skip of fully-masked tiles
      f32x4 s0 = {0.f, 0.f, 0.f, 0.f}, s1 = {0.f, 0.f, 0.f, 0.f};
#pragma unroll
      for (int kc = 0; kc < 8; ++kc) {
        const int c16 = kc * 4 + quad;
        const int cs = (c16 & 24) | ((c16 & 7) ^ lo7);
        s16x8 kf0 = *(const s16x8*)&SH[(lo * 32 + cs) * 8];
        s16x8 kf1 = *(const s16x8*)&SH[((16 + lo) * 32 + cs) * 8];
        s0 = __builtin_amdgcn_mfma_f32_16x16x32_bf16(qf[kc], kf0, s0, 0, 0, 0);
        s1 = __builtin_amdgcn_mfma_f32_16x16x32_bf16(qf[kc], kf1, s1, 0, 0, 0);
      }
      if (k0 + 31 > qr0) {  // straddling tile: causal mask
#pragma unroll
        for (int ii = 0; ii < 4; ++ii) {
          const int row = qr0 + quad * 4 + ii;
          if (k0 + lo > row) s0[ii] = -1e30f;
          if (k0 + 16 + lo > row) s1[ii] = -1e30f;
        }
      }
      // static-M softmax: p = exp(s - M); no max tracking, no O rescale
#pragma unroll
      for (int ii = 0; ii < 4; ++ii) {
        myp[(quad * 4 + ii) * 40 + lo]      = f2bf(__expf(s0[ii] - SM_M));
        myp[(quad * 4 + ii) * 40 + 16 + lo] = f2bf(__expf(s1[ii] - SM_M));
      }
      s16x8 pf = *(const s16x8*)&myp[lo * 40 + quad * 8];
      Ol = __builtin_amdgcn_mfma_f32_16x16x32_bf16(pf, ones, Ol, 0, 0, 0);
#pragma unroll
      for (int nt = 0; nt < 16; ++nt) {
        const int d = nt * 16 + lo;
        const int cp = quad ^ ((d >> 1) & 3);
        s16x8 vf = *(const s16x8*)&SH[8192 + ((d << 2) + cp) * 8];
        O[nt] = __builtin_amdgcn_mfma_f32_16x16x32_bf16(pf, vf, O[nt], 0, 0, 0);
      }
    }
  }
  __syncthreads();  // all waves done with K/V/P before OL overlay

  // ---- epilogue (wave-local): normalize O -> LDS A-layout -> head GEMM -> MSE ----
  float inv4[4];
#pragma unroll
  for (int ii = 0; ii < 4; ++ii) inv4[ii] = 1.f / Ol[ii];
  unsigned short* OLw = &SH[w * 4224];
#pragma unroll
  for (int nt = 0; nt < 16; ++nt)
#pragma unroll
    for (int ii = 0; ii < 4; ++ii)
      OLw[(quad * 4 + ii) * 264 + nt * 16 + lo] = f2bf(O[nt][ii] * inv4[ii]);

  s16x8 af[8];
#pragma unroll
  for (int kc = 0; kc < 8; ++kc)
    af[kc] = *(const s16x8*)&OLw[lo * 264 + kc * 32 + quad * 8];

  const float S = sget[b * 2], SS = sget[b * 2 + 1];
  const float mean = S * (1.f / (float)L_SZ);
  const float var = (SS - S * mean) * (1.f / (float)(L_SZ - 1));
  const float invb = 1.f / (sqrtf(var) + 1e-5f);

  float lacc = 0.f;
#pragma unroll
  for (int nt = 0; nt < 2; ++nt) {
    f32x4 acc = {0.f, 0.f, 0.f, 0.f};
#pragma unroll
    for (int kc = 0; kc < 8; ++kc) {
      s16x8 bfr = *(const s16x8*)&WfT[(size_t)(nt * 16 + lo) * 256 + kc * 32 + quad * 8];
      acc = __builtin_amdgcn_mfma_f32_16x16x32_bf16(af[kc], bfr, acc, 0, 0, 0);
    }
    const float ba = bfp[nt * 16 + lo];
    const int p = nt * 16 + lo;
#pragma unroll
    for (int ii = 0; ii < 4; ++ii) {
      const int t = qr0 + quad * 4 + ii;
      if (t < 1023) {
        const float pr = acc[ii] + ba;
        const float tg = (x[(size_t)b * L_SZ + (t + 1) * 32 + p] - mean) * invb;
        const float d = pr - tg;
        lacc += d * d;
      }
    }
  }
#pragma unroll
  for (int off = 32; off >= 1; off >>= 1) lacc += __shfl_down(lacc, off);
  if (lane == 0) atomicAdd(lsum, lacc);
}

__global__ void finalize_kernel(const float* __restrict__ lsum, float* __restrict__ out) {
  out[0] = lsum[0] * (1.f / (float)(B_SZ * (T_SZ - 1) * PS_SZ));
}

extern "C" void kernel_launch(void* const* d_in, const int* in_sizes, int n_in,
                              void* d_out, int out_size, void* d_ws, size_t ws_size,
                              hipStream_t stream) {
  const float* x      = (const float*)d_in[0];
  const float* W_proj = (const float*)d_in[1];
  const float* b_proj = (const float*)d_in[2];
  const float* W_qkv  = (const float*)d_in[3];
  const float* b_qkv  = (const float*)d_in[4];
  const float* W_out  = (const float*)d_in[5];
  const float* b_out  = (const float*)d_in[6];
  const float* W_head = (const float*)d_in[7];
  const float* b_head = (const float*)d_in[8];
  float* out = (float*)d_out;

  char* ws = (char*)d_ws;
  unsigned short* Qb  = (unsigned short*)(ws);                  // 16MB
  unsigned short* Kb  = (unsigned short*)(ws + (16ull << 20));  // 16MB
  unsigned short* Vtt = (unsigned short*)(ws + (32ull << 20));  // 16MB, kt-tiled V^T
  char* tail = ws + (48ull << 20);
  float*          Wcb  = (float*)(tail);                          // 768 fp32 folded qkv bias
  unsigned short* WqT  = (unsigned short*)(tail + (4ull << 10));  // 768x32 bf16
  unsigned short* WfT  = (unsigned short*)(tail + (64ull << 10)); // 32x256 bf16
  float*          bfp  = (float*)(tail + (96ull << 10));          // 32 fp32
  float*          sget = (float*)(tail + (100ull << 10));         // 64 fp32 stats
  float*          lsum = (float*)(tail + (100ull << 10) + 256);   // 1 fp32

  hipMemsetAsync(sget, 0, 512, stream);  // sget + lsum
  prep_kernel<<<388, 256, 0, stream>>>(x, sget, W_proj, b_proj, W_qkv, b_qkv,
                                       W_out, b_out, W_head, b_head,
                                       Wcb, WqT, WfT, bfp);
  gemm_qkv_mfma<<<256, 256, 0, stream>>>(x, sget, WqT, Wcb, Qb, Kb, Vtt);
  attn_kernel<<<512, 256, 0, stream>>>(Qb, Kb, Vtt, WfT, bfp, x, sget, lsum);
  finalize_kernel<<<1, 1, 0, stream>>>(lsum, out);
}